// Round 14
// baseline (135.732 us; speedup 1.0000x reference)
//
#include <hip/hip_runtime.h>

typedef __attribute__((ext_vector_type(8))) short short8;
typedef __attribute__((ext_vector_type(4))) float f32x4;
typedef __attribute__((ext_vector_type(16))) float f32x16;

#define ROWS 16384   // B*N
#define DIM 64
#define NCODES 8192
#define MARGIN 0.008f
#define KT_FB 256
#define TILES_PER_BLOCK 16  // 16 tiles x 32 codes = 512 codes per y-block

// ws layout (bytes)
#define WS_BEST   0            // 16384 * 8
#define WS_COUNTS 131072       // 8192 * 4
#define WS_ENH    163840       // 8192 * 4
#define WS_ESWZ   196608       // 256 tiles * 8 frags * 64 lanes * 16B = 2 MB
#define WS_NEED   2293760

__device__ __forceinline__ unsigned long long pack_score(float s, int idx) {
  unsigned u = __float_as_uint(s);
  u ^= (unsigned)((int)u >> 31) | 0x80000000u;
  return ((unsigned long long)u << 32) | (unsigned)(0xFFFF - idx);
}
__device__ __forceinline__ unsigned short bf16hi(float f) {
  unsigned u = __float_as_uint(f);
  return (unsigned short)((u + 0x7FFFu + ((u >> 16) & 1u)) >> 16);
}

__global__ void vq_enorm(const float* __restrict__ embed, float* __restrict__ enh) {
  int k = blockIdx.x * 256 + threadIdx.x;
  const float4* e4 = (const float4*)(embed + (size_t)k * DIM);
  float a = 0.f, b = 0.f, c = 0.f, d = 0.f;
#pragma unroll
  for (int i = 0; i < DIM / 4; ++i) {
    float4 v = e4[i];
    a = fmaf(v.x, v.x, a); b = fmaf(v.y, v.y, b);
    c = fmaf(v.z, v.z, c); d = fmaf(v.w, v.w, d);
  }
  enh[k] = 0.5f * ((a + b) + (c + d));
}

// Pre-swizzle embed into 32x32x16 MFMA B-fragment order, split hi/lo bf16.
// Tile = 32 codes. Frag fi: 0..3 = hi(kc=fi), 4..7 = lo(kc=fi&3).
// Lane l of frag (tile,fi): code = tile*32+(l&31), k = kc*16+(l>>5)*8+j.
__global__ void vq_prep_e(const float* __restrict__ embed, short* __restrict__ eswz) {
  int u = blockIdx.x * 256 + threadIdx.x;  // 131072 = 256 tiles * 8 frags * 64
  int l = u & 63, fi = (u >> 6) & 7, tile = u >> 9;
  int term = fi >> 2, kc = fi & 3;
  int code = tile * 32 + (l & 31);
  int kb = kc * 16 + (l >> 5) * 8;
  const float* er = embed + (size_t)code * DIM + kb;
  short8 h8, l8;
#pragma unroll
  for (int j = 0; j < 8; ++j) {
    float v = er[j];
    unsigned short h = bf16hi(v);
    float r = v - __uint_as_float((unsigned)h << 16);
    h8[j] = (short)h;
    l8[j] = (short)bf16hi(r);
  }
  ((short8*)eswz)[u] = term ? l8 : h8;
}

#define MFMA32(A, B, C) __builtin_amdgcn_mfma_f32_32x32x16_bf16((A), (B), (C), 0, 0, 0)

// Screen, r14: 32x32x16 MFMA. r5-r13 invariant (~95us, MfmaUtil 22, VALUBusy 37
// across 9 staging/occupancy/chain variants incl. 72%-occupancy r11) says the
// kernel is instruction-ISSUE-bound, not stall-bound: ~84 VALU + 12 MFMA issues
// per 16-code ct. Fix = fewer, bigger instructions: one 32x32x16 MFMA covers
// 32 codes (half the MFMA instrs/code, 2495 vs 2075 TF pipe rate). Wave = 32
// rows x 512 codes as 16 tiles; 12 MFMAs/tile (3 split terms x 4 k-chunks) into
// one f32x16 acc. A/B built with symmetric (lane,j)->k rule (permutation-safe);
// C/D mapping col=lane&31, row=(reg&3)+8*(reg>>2)+4*(lane>>5) [m74/m101].
// Direct-L2 B loads (no LDS/barriers - proven equal). Float top-1 compare,
// margin-gated exact fp32 rescore, packed u64 atomicMax (bit-exact argmax).
__global__ __launch_bounds__(256, 4) void vq_screen(
    const float* __restrict__ x, const float* __restrict__ embed,
    const short* __restrict__ eswz, const float* __restrict__ enh,
    unsigned long long* __restrict__ best) {
  const int t = threadIdx.x;
  const int l = t & 63, wid = t >> 6;
  const int c32 = l & 31, half = l >> 5;
  const int row0 = blockIdx.x * 128 + wid * 32;
  const int ty0 = blockIdx.y * TILES_PER_BLOCK;

  // A fragments: rows row0+(l&31), k = kc*16 + half*8 + j, hi/lo split.
  short8 ahi[4], alo[4];
  {
    const float* xr = x + (size_t)(row0 + c32) * DIM;
#pragma unroll
    for (int kc = 0; kc < 4; ++kc) {
      const float4* p = (const float4*)(xr + kc * 16 + half * 8);
      float4 v0 = p[0], v1 = p[1];
      float vv[8] = {v0.x, v0.y, v0.z, v0.w, v1.x, v1.y, v1.z, v1.w};
#pragma unroll
      for (int j = 0; j < 8; ++j) {
        unsigned short h = bf16hi(vv[j]);
        float r = vv[j] - __uint_as_float((unsigned)h << 16);
        ahi[kc][j] = (short)h;
        alo[kc][j] = (short)bf16hi(r);
      }
    }
  }

  float bsc[16];
  int bidx[16];
#pragma unroll
  for (int r = 0; r < 16; ++r) { bsc[r] = -3.4e38f; bidx[r] = 0; }

  const short8* eb = (const short8*)eswz + (size_t)ty0 * 8 * 64;

#pragma unroll 2
  for (int ct = 0; ct < TILES_PER_BLOCK; ++ct) {
    const short8* bt = eb + (size_t)ct * 512;  // 8 frags x 64 lanes
    const float eh = enh[(ty0 + ct) * 32 + c32];  // consumed 12 MFMAs later

    // hi frags, 8 MFMAs (terms hi*hi, lo*hi) -- bh dead before bl loads
    short8 bh0 = bt[0 * 64 + l], bh1 = bt[1 * 64 + l];
    short8 bh2 = bt[2 * 64 + l], bh3 = bt[3 * 64 + l];

    f32x16 acc;
#pragma unroll
    for (int r = 0; r < 16; ++r) acc[r] = 0.f;

    acc = MFMA32(ahi[0], bh0, acc);
    acc = MFMA32(ahi[1], bh1, acc);
    acc = MFMA32(ahi[2], bh2, acc);
    acc = MFMA32(ahi[3], bh3, acc);
    acc = MFMA32(alo[0], bh0, acc);
    acc = MFMA32(alo[1], bh1, acc);
    acc = MFMA32(alo[2], bh2, acc);
    acc = MFMA32(alo[3], bh3, acc);

    // lo frags, 4 MFMAs (term hi*lo); loads overlap the lo*hi MFMAs above
    short8 bl0 = bt[4 * 64 + l], bl1 = bt[5 * 64 + l];
    short8 bl2 = bt[6 * 64 + l], bl3 = bt[7 * 64 + l];
    acc = MFMA32(ahi[0], bl0, acc);
    acc = MFMA32(ahi[1], bl1, acc);
    acc = MFMA32(ahi[2], bl2, acc);
    acc = MFMA32(ahi[3], bl3, acc);

#pragma unroll
    for (int r = 0; r < 16; ++r) {
      float s = acc[r] - eh;
      if (s > bsc[r]) { bsc[r] = s; bidx[r] = ct; }
    }
  }

  // Row max across the 32 lanes holding each row (xor 1..16 stays in half);
  // flag lane-bests within margin.
  unsigned fmask = 0;
#pragma unroll
  for (int r = 0; r < 16; ++r) {
    float m = bsc[r];
    m = fmaxf(m, __shfl_xor(m, 1));
    m = fmaxf(m, __shfl_xor(m, 2));
    m = fmaxf(m, __shfl_xor(m, 4));
    m = fmaxf(m, __shfl_xor(m, 8));
    m = fmaxf(m, __shfl_xor(m, 16));
    if (bsc[r] >= m - MARGIN) fmask |= 1u << r;
  }

  // Exact fp32 rescore of flagged candidates, lane-compacted.
  float exact[16];
#pragma unroll
  for (int r = 0; r < 16; ++r) exact[r] = -3.4e38f;

  while (__any((int)(fmask != 0))) {
    const bool act = fmask != 0;
    const int sel = act ? __ffs(fmask) - 1 : 0;
    int ctl = 0;
#pragma unroll
    for (int r = 0; r < 16; ++r) ctl = (sel == r) ? bidx[r] : ctl;
    int code = act ? (ty0 + ctl) * 32 + c32 : 0;
    int row = act ? row0 + (sel & 3) + 8 * (sel >> 2) + 4 * half : row0;
    const float4* xr = (const float4*)(x + (size_t)row * DIM);
    const float4* er = (const float4*)(embed + (size_t)code * DIM);
    float a0 = 0, a1 = 0, a2 = 0, a3 = 0, n0 = 0, n1 = 0, n2 = 0, n3 = 0;
#pragma unroll
    for (int i = 0; i < 16; ++i) {
      float4 xv = xr[i], ev = er[i];
      a0 = fmaf(xv.x, ev.x, a0); a1 = fmaf(xv.y, ev.y, a1);
      a2 = fmaf(xv.z, ev.z, a2); a3 = fmaf(xv.w, ev.w, a3);
      n0 = fmaf(ev.x, ev.x, n0); n1 = fmaf(ev.y, ev.y, n1);
      n2 = fmaf(ev.z, ev.z, n2); n3 = fmaf(ev.w, ev.w, n3);
    }
    float ex = ((a0 + a1) + (a2 + a3)) - 0.5f * ((n0 + n1) + (n2 + n3));
#pragma unroll
    for (int r = 0; r < 16; ++r)
      exact[r] = (act && sel == r) ? ex : exact[r];
    fmask = act ? (fmask & (fmask - 1)) : 0u;
  }

  // (exact score, lowest-idx) reduce across the 32 lanes of each row; atomicMax.
#pragma unroll
  for (int r = 0; r < 16; ++r) {
    unsigned long long pk = pack_score(exact[r], (ty0 + bidx[r]) * 32 + c32);
    unsigned long long o;
    o = __shfl_xor(pk, 1); pk = pk > o ? pk : o;
    o = __shfl_xor(pk, 2); pk = pk > o ? pk : o;
    o = __shfl_xor(pk, 4); pk = pk > o ? pk : o;
    o = __shfl_xor(pk, 8); pk = pk > o ? pk : o;
    o = __shfl_xor(pk, 16); pk = pk > o ? pk : o;
    if (c32 == 0)
      atomicMax(&best[row0 + (r & 3) + 8 * (r >> 2) + 4 * half], pk);
  }
}

// Fallback (proven round-1 path) if ws is too small for the MFMA screen.
__global__ __launch_bounds__(256, 2) void vq_score_fb(
    const float* __restrict__ x, const float* __restrict__ embed,
    const float* __restrict__ enh, unsigned long long* __restrict__ best) {
  const int row = blockIdx.x * 256 + threadIdx.x;
  const int c0 = blockIdx.y * KT_FB;
  float4 xa[16];
  const float4* xg = (const float4*)(x + (size_t)row * DIM);
#pragma unroll
  for (int i = 0; i < 16; ++i) xa[i] = xg[i];
  float bs = -3.4e38f;
  int bc = 0;
#pragma unroll 2
  for (int c = c0; c < c0 + KT_FB; ++c) {
    const float4* e4 = (const float4*)(embed + (size_t)c * DIM);
    float a0 = 0.f, a1 = 0.f, a2 = 0.f, a3 = 0.f;
#pragma unroll
    for (int i = 0; i < 16; ++i) {
      float4 ev = e4[i];
      a0 = fmaf(xa[i].x, ev.x, a0); a1 = fmaf(xa[i].y, ev.y, a1);
      a2 = fmaf(xa[i].z, ev.z, a2); a3 = fmaf(xa[i].w, ev.w, a3);
    }
    float s = ((a0 + a1) + (a2 + a3)) - enh[c];
    if (s > bs) { bs = s; bc = c; }
  }
  atomicMax(&best[row], pack_score(bs, bc));
}

__global__ void vq_finalize(const unsigned long long* __restrict__ best,
                            const float* __restrict__ embed,
                            const float* __restrict__ node_mask,
                            float* __restrict__ quant,
                            float* __restrict__ out_idx,
                            float* __restrict__ counts) {
  int gid = blockIdx.x * 256 + threadIdx.x;
  int row = gid >> 6, d = gid & 63;
  unsigned long long p = best[row];
  int idx = 0xFFFF - (int)(p & 0xFFFFull);
  quant[gid] = embed[(size_t)idx * DIM + d];
  if (d == 0) {
    out_idx[row] = (float)idx;
    atomicAdd(&counts[idx], node_mask[row]);
  }
}

__global__ void vq_perplexity(const float* __restrict__ counts, float* __restrict__ out) {
  int tid = threadIdx.x;
  float acc = 0.f;
  for (int k = tid; k < NCODES; k += 256) {
    float p = counts[k] * (1.0f / (float)ROWS);
    acc += p * logf(p + 1e-10f);
  }
#pragma unroll
  for (int off = 32; off > 0; off >>= 1) acc += __shfl_down(acc, off);
  __shared__ float red[4];
  if ((tid & 63) == 0) red[tid >> 6] = acc;
  __syncthreads();
  if (tid == 0) out[0] = expf(-((red[0] + red[1]) + (red[2] + red[3])));
}

extern "C" void kernel_launch(void* const* d_in, const int* in_sizes, int n_in,
                              void* d_out, int out_size, void* d_ws, size_t ws_size,
                              hipStream_t stream) {
  const float* x = (const float*)d_in[0];
  const float* node_mask = (const float*)d_in[1];
  const float* embed = (const float*)d_in[2];

  float* out = (float*)d_out;
  float* quant = out;
  float* out_idx = out + (size_t)ROWS * DIM;
  float* out_ppl = out_idx + ROWS;

  unsigned long long* best = (unsigned long long*)((char*)d_ws + WS_BEST);
  float* counts = (float*)((char*)d_ws + WS_COUNTS);
  float* enh = (float*)((char*)d_ws + WS_ENH);
  short* eswz = (short*)((char*)d_ws + WS_ESWZ);

  hipMemsetAsync(d_ws, 0, WS_ENH, stream);  // best + counts
  vq_enorm<<<NCODES / 256, 256, 0, stream>>>(embed, enh);
  if (ws_size >= WS_NEED) {
    vq_prep_e<<<512, 256, 0, stream>>>(embed, eswz);
    vq_screen<<<dim3(ROWS / 128, NCODES / (TILES_PER_BLOCK * 32)), 256, 0, stream>>>(
        x, embed, eswz, enh, best);
  } else {
    vq_score_fb<<<dim3(ROWS / 256, NCODES / KT_FB), 256, 0, stream>>>(x, embed, enh, best);
  }
  vq_finalize<<<ROWS * DIM / 256, 256, 0, stream>>>(best, embed, node_mask, quant, out_idx, counts);
  vq_perplexity<<<1, 256, 0, stream>>>(counts, out_ppl);
}